// Round 4
// baseline (315.667 us; speedup 1.0000x reference)
//
#include <hip/hip_runtime.h>

// VQ-VAE forward on MI355X, fp32 (no fp32 MFMA on CDNA4 -> vector ALU).
// N = 65536 rows, IN_DIM=256, D=64, K=512.
//
// ws layout (bytes):
//   z:      float[65536*64]        @ 0          (16 MiB)
//   part:   ull[65536]             @ 16777216   (512 KiB)  argmin keys
//   cr:     float[512*256]         @ 17301504   (512 KiB)  = codebook @ dec_w
//   counts: int[512]               @ 17825792   (2 KiB)
//   spart:  double[2048]           @ 17827840   (16 KiB)   per-block sse partials
//   eesq:   float[512]             @ 17844224   (2 KiB)    ||e||^2 per code
//
// v5 = v4 with the k_encode LDS-alignment bug fixed (v4 staged x with
// float4 stores at pitch 66 floats = 264 B -> odd rows 8B-misaligned
// ds_write_b128 -> GPU fault/hang).  Now pitch 65 + four ds_write_b32
// (cannot be merged to b128 without alignment proof -> safe); read bank
// (l+kk)%32 -> 2-way = free.
//
// Theory (unchanged from v4): v3's k_assign was LDS-return-path bound
// (4.19M broadcast ds_read_b128 x 12cyc = 82us ~= 92us measured; VALU floor
// 27us).  The wave-SHARED operand (codebook/weight row) is wave-uniform ->
// stream it through SGPRs via s_load (scalar pipe, no LDS, no VMEM);
// v_fma takes one SGPR source.  Per-lane private data (z row / acc) stays
// pinned in VGPRs.  All fmaf chain orders preserved bit-exactly.

__device__ __forceinline__ unsigned ford(float s) {
    // order-preserving map float -> unsigned (total order, matches < on floats)
    unsigned b = __float_as_uint(s);
    return (b & 0x80000000u) ? ~b : (b | 0x80000000u);
}

// ---------------- K1: z = x @ enc_w  ([65536,256]x[256,64]) ----------------
// 512 blocks x 128 thr (2 waves); lane owns ONE output row: acc[64] in VGPRs.
// x chunk staged in LDS pitch 65 (read bank (l+kk)%32 -> 2-way, free);
// enc_w row (uniform addr) -> s_load into SGPRs; per kk: 1 ds_read_b32 +
// 64 v_fma(VGPR, SGPR, VGPR).  LDS pipe ~5us total (was ~80-90us broadcast).
// Chain: acc[d] += x[k]*w[k][d] for k ascending == the verified nested-fmaf
// order (x.x,w0 .. x.w,w3 ascending k) -> bit-identical z.
__global__ __launch_bounds__(128) void k_encode(const float* __restrict__ x,
                                                const float* __restrict__ enc_w,
                                                float* __restrict__ z) {
    __shared__ float xs[128 * 65];  // pitch 65 floats, 33280 B -> 4 blocks/CU

    int t = threadIdx.x;
    int row0 = blockIdx.x * 128;

    float acc[64];
#pragma unroll
    for (int d = 0; d < 64; ++d) acc[d] = 0.f;

    const float4* xg = (const float4*)x;  // x row = 64 float4

    for (int c = 0; c < 4; ++c) {
        __syncthreads();  // prior chunk's readers done
        // stage chunk: 2048 f4; thread t -> rows (t>>4)+8j, f4 col (t&15).
        // b32 stores (pitch 65 is unprovably-aligned for b128 -> stays b32):
        // banks 2-way across the wave -> free.
#pragma unroll
        for (int j = 0; j < 16; ++j) {
            int r = (t >> 4) + 8 * j;
            float4 v = xg[(size_t)(row0 + r) * 64 + c * 16 + (t & 15)];
            float* p = &xs[r * 65 + (t & 15) * 4];
            p[0] = v.x;
            p[1] = v.y;
            p[2] = v.z;
            p[3] = v.w;
        }
        __syncthreads();

#pragma unroll 2
        for (int kk = 0; kk < 64; ++kk) {
            float xv = xs[t * 65 + kk];  // 2-way bank alias: free
            const float* w = enc_w + (size_t)(c * 64 + kk) * 64;  // uniform -> s_load
#pragma unroll
            for (int d = 0; d < 64; ++d) acc[d] = fmaf(xv, w[d], acc[d]);
        }
    }
    float4* z4 = (float4*)(z + (size_t)(row0 + t) * 64);
#pragma unroll
    for (int j = 0; j < 16; ++j)
        z4[j] = make_float4(acc[4 * j + 0], acc[4 * j + 1], acc[4 * j + 2], acc[4 * j + 3]);
}

// ---------------- K2: nearest-code assignment ----------------
// 1024 blocks (quarter-major: bid = q*256 + row_tile) x 256 thr (4 waves).
// Lane owns ONE z-row pinned in 64 VGPRs; iterates its quarter's 128 codes.
// Per code: 4x s_load_dwordx16 (codebook row, uniform addr) + 64 FMA w/ SGPR
// operand + key update.  ZERO LDS in the loop.  ~80 VGPR -> ~24 waves/CU
// for scalar-latency hiding.  Per-lane best key -> one u64 atomicMin per
// (row, quarter).
// NUMERICS: d0..d3 fmaf chains ascending j, s=(zz+ee)-2f*dot, min-key
// tie-break lowest code -> bit-identical argmin to verified versions.
__global__ __launch_bounds__(256) void k_assign(const float* __restrict__ z,
                                                const float* __restrict__ cb,
                                                const float* __restrict__ eesq,
                                                unsigned long long* __restrict__ part) {
    int t = threadIdx.x, lane = t & 63, wv = t >> 6;
    int q = blockIdx.x >> 8;    // code quarter (4)
    int rt = blockIdx.x & 255;  // row tile (256)
    int c0 = q * 128;
    int row = rt * 256 + wv * 64 + lane;  // lane's row

    // load lane's z-row into regs and PIN (prevent remat-from-global)
    const float4* zr4 = (const float4*)z + (size_t)row * 16;
    float4 zr[16];
#pragma unroll
    for (int j = 0; j < 16; ++j) zr[j] = zr4[j];
#pragma unroll
    for (int j = 0; j < 16; ++j)
        asm volatile("" : "+v"(zr[j].x), "+v"(zr[j].y), "+v"(zr[j].z), "+v"(zr[j].w));

    // zz from regs (exact verified chain)
    float zz;
    {
        float a0 = 0, a1 = 0, a2 = 0, a3 = 0;
#pragma unroll
        for (int j = 0; j < 16; ++j) {
            a0 = fmaf(zr[j].x, zr[j].x, a0);
            a1 = fmaf(zr[j].y, zr[j].y, a1);
            a2 = fmaf(zr[j].z, zr[j].z, a2);
            a3 = fmaf(zr[j].w, zr[j].w, a3);
        }
        zz = (a0 + a1) + (a2 + a3);
    }

    unsigned long long best = ~0ull;
#pragma unroll 2
    for (int c = 0; c < 128; ++c) {
        const float* e = cb + (size_t)(c0 + c) * 64;  // uniform addr -> s_load
        float d0 = 0, d1 = 0, d2 = 0, d3 = 0;
#pragma unroll
        for (int j = 0; j < 16; ++j) {
            d0 = fmaf(zr[j].x, e[4 * j + 0], d0);
            d1 = fmaf(zr[j].y, e[4 * j + 1], d1);
            d2 = fmaf(zr[j].z, e[4 * j + 2], d2);
            d3 = fmaf(zr[j].w, e[4 * j + 3], d3);
        }
        float ee = eesq[c0 + c];  // uniform -> s_load
        float dot = (d0 + d1) + (d2 + d3);
        float s = (zz + ee) - 2.0f * dot;  // reference-matching fp32 rounding
        unsigned long long k = ((unsigned long long)ford(s) << 32) | (unsigned)(c0 + c);
        if (k < best) best = k;
    }
    atomicMin(&part[row], best);
}

// ---------------- K3a: cr = codebook @ dec_w + eesq ----------------
// 16 blocks x 256 threads; block does 32 codes; dec_w streamed from L2.
// acc chain identical to verified version -> cr bit-identical.  Also emits
// eesq[code] = ||e||^2 with the exact verified n0..n3 chain (hoisted out of
// k_assign so assign does zero redundant work).
__global__ __launch_bounds__(256) void k_coderecon(const float* __restrict__ cb,
                                                   const float* __restrict__ dec_w,
                                                   float* __restrict__ cr,
                                                   float* __restrict__ eesq) {
    __shared__ float qs[32 * 64];  // 8 KB

    int t = threadIdx.x;
    int r0 = blockIdx.x * 32;
    {
        const float4* cb4 = (const float4*)cb;
        float4* qs4 = (float4*)qs;
#pragma unroll
        for (int j = 0; j < 2; ++j) qs4[t + 256 * j] = cb4[r0 * 16 + t + 256 * j];
    }
    __syncthreads();

    if (t < 32) {  // eesq: exact verified 4-chain
        const float4* q4 = (const float4*)qs + t * 16;
        float n0 = 0, n1 = 0, n2 = 0, n3 = 0;
#pragma unroll
        for (int j = 0; j < 16; ++j) {
            float4 e = q4[j];
            n0 = fmaf(e.x, e.x, n0);
            n1 = fmaf(e.y, e.y, n1);
            n2 = fmaf(e.z, e.z, n2);
            n3 = fmaf(e.w, e.w, n3);
        }
        eesq[r0 + t] = (n0 + n1) + (n2 + n3);
    }

    int l = t & 63, w = t >> 6;  // wave w -> codes w*8..w*8+7; lane -> 4 columns
    const float4* dw4 = (const float4*)dec_w;
    float4 acc[8];
#pragma unroll
    for (int j = 0; j < 8; ++j) acc[j] = make_float4(0.f, 0.f, 0.f, 0.f);

#pragma unroll 4
    for (int d = 0; d < 64; ++d) {
        float4 wv = dw4[d * 64 + l];  // global, coalesced, L2-resident
#pragma unroll
        for (int j = 0; j < 8; ++j) {
            float qv = qs[(w * 8 + j) * 64 + d];  // broadcast (tiny kernel)
            acc[j].x = fmaf(qv, wv.x, acc[j].x);
            acc[j].y = fmaf(qv, wv.y, acc[j].y);
            acc[j].z = fmaf(qv, wv.z, acc[j].z);
            acc[j].w = fmaf(qv, wv.w, acc[j].w);
        }
    }
    float4* cr4 = (float4*)cr;
#pragma unroll
    for (int j = 0; j < 8; ++j) cr4[(size_t)(r0 + w * 8 + j) * 64 + l] = acc[j];
}

// ---------------- K3b: fused finish: gather + sse + counts ----------------
// 2048 blocks x 256 thr; wave = 8 rows.  LDS hist cuts global atomics to
// <=nonzero-codes per block.  Stores: lane l writes out1[row*256 + l + 64j]
// -> 256 B contiguous dword segments (out is 4B-aligned only).
__global__ __launch_bounds__(256) void k_finish(const unsigned long long* __restrict__ part,
                                                const float* __restrict__ z,
                                                const float* __restrict__ cb,
                                                const float* __restrict__ cr,
                                                float* __restrict__ out1,
                                                double* __restrict__ spart,
                                                int* __restrict__ counts) {
    __shared__ double red[4];
    __shared__ int hist[512];
    int t = threadIdx.x, l = t & 63, w = t >> 6;
    int row0 = blockIdx.x * 32 + w * 8;

    hist[t] = 0;
    hist[t + 256] = 0;
    __syncthreads();

    unsigned long long myk = part[row0 + (l & 7)];  // 8 keys, 8-way duplicated
    double acc = 0.0;
#pragma unroll
    for (int i = 0; i < 8; ++i) {
        int row = row0 + i;
        int kb = (int)(__shfl(myk, i) & 0xffffffffu);
        if (l == 0) atomicAdd(&hist[kb], 1);
        // sse slice: this lane handles dim d = l
        float zv = z[(size_t)row * 64 + l];
        float qv = cb[(size_t)kb * 64 + l];
        float f = qv - zv;
        acc += (double)f * f;
        // reconstruction row copy
        const float* crr = cr + (size_t)kb * 256;
        float* o = out1 + (size_t)row * 256;
#pragma unroll
        for (int j = 0; j < 4; ++j) o[l + 64 * j] = crr[l + 64 * j];
    }
#pragma unroll
    for (int off = 32; off >= 1; off >>= 1) acc += __shfl_down(acc, off);
    if (l == 0) red[w] = acc;
    __syncthreads();
    if (t == 0) spart[blockIdx.x] = (red[0] + red[1]) + (red[2] + red[3]);
    if (hist[t]) atomicAdd(&counts[t], hist[t]);
    if (hist[t + 256]) atomicAdd(&counts[t + 256], hist[t + 256]);
}

// ---------------- K4: loss + perplexity scalars ----------------
__global__ __launch_bounds__(512) void k_final(const double* __restrict__ spart,
                                               const int* __restrict__ counts,
                                               float* __restrict__ out_loss,
                                               float* __restrict__ out_pp) {
    __shared__ double redp[8], reds[8];
    int t = threadIdx.x;
    double p = (double)counts[t] / 65536.0;
    double term = p * log(p + 1e-10);
    double s = 0.0;
#pragma unroll
    for (int j = 0; j < 4; ++j) s += spart[t + 512 * j];
#pragma unroll
    for (int off = 32; off >= 1; off >>= 1) {
        term += __shfl_down(term, off);
        s += __shfl_down(s, off);
    }
    if ((t & 63) == 0) {
        redp[t >> 6] = term;
        reds[t >> 6] = s;
    }
    __syncthreads();
    if (t == 0) {
        double st = 0, ss = 0;
#pragma unroll
        for (int w = 0; w < 8; ++w) {
            st += redp[w];
            ss += reds[w];
        }
        out_pp[0] = (float)exp(-st);
        out_loss[0] = (float)(1.25 * ss / 4194304.0);  // (1+0.25)*mean((q-z)^2)
    }
}

extern "C" void kernel_launch(void* const* d_in, const int* in_sizes, int n_in,
                              void* d_out, int out_size, void* d_ws, size_t ws_size,
                              hipStream_t stream) {
    const float* x = (const float*)d_in[0];
    const float* enc_w = (const float*)d_in[1];
    const float* dec_w = (const float*)d_in[2];
    const float* cb = (const float*)d_in[3];
    float* out = (float*)d_out;

    char* ws = (char*)d_ws;
    float* z = (float*)ws;                                            // 16 MiB
    unsigned long long* part = (unsigned long long*)(ws + 16777216);  // 512 KiB
    float* cr = (float*)(ws + 17301504);                              // 512 KiB
    int* counts = (int*)(ws + 17825792);                              // 2 KiB
    double* spart = (double*)(ws + 17827840);                         // 16 KiB
    float* eesq = (float*)(ws + 17844224);                            // 2 KiB

    // ws is poisoned to 0xAA before each launch
    hipMemsetAsync(ws + 16777216, 0xFF, 524288, stream);  // part -> max keys
    hipMemsetAsync(ws + 17825792, 0, 2048, stream);       // counts -> 0

    k_coderecon<<<dim3(16), dim3(256), 0, stream>>>(cb, dec_w, cr, eesq);
    k_encode<<<dim3(512), dim3(128), 0, stream>>>(x, enc_w, z);
    k_assign<<<dim3(1024), dim3(256), 0, stream>>>(z, cb, eesq, part);
    k_finish<<<dim3(2048), dim3(256), 0, stream>>>(part, z, cb, cr, out + 1, spart, counts);
    k_final<<<dim3(1), dim3(512), 0, stream>>>(spart, counts, out, out + 16777217);
}

// Round 5
// 256.022 us; speedup vs baseline: 1.2330x; 1.2330x over previous
//
#include <hip/hip_runtime.h>

// VQ-VAE forward on MI355X, fp32 (no fp32 MFMA on CDNA4 -> vector ALU).
// N = 65536 rows, IN_DIM=256, D=64, K=512.
//
// ws layout (bytes):
//   z:      float[65536*64]        @ 0          (16 MiB)
//   part:   ull[65536]             @ 16777216   (512 KiB)  argmin keys
//   cr:     float[512*256]         @ 17301504   (512 KiB)  = codebook @ dec_w
//   counts: int[512]               @ 17825792   (2 KiB)
//   spart:  double[2048]           @ 17827840   (16 KiB)   per-block sse partials
//   eesq:   float[512]             @ 17844224   (2 KiB)    ||e||^2 per code
//
// v6: v5's k_encode was scalar-LATENCY bound, not scalar-throughput bound:
// OccupancyPercent 11% (512 blocks x 2 waves = 4 waves/CU) and 64 SGPRs of
// w per kk (no prefetch depth) -> VALUBusy 12%.  Fix: split the 64 output
// dims across the block's 4 waves (wave dq owns d in [dq*16, dq*16+16) for
// all 64 rows).  Per kk: 1 ds_read_b32 (x) + ONE s_load_dwordx16 (16 w
// floats; ~4 in flight fit SGPRs) + 16 FMA.  1024 blocks x 256 thr,
// 16.6 KB LDS -> 4 blocks/CU = 16 waves/CU.  dq goes through
// readfirstlane so the w pointer is PROVABLY uniform (else divergence
// analysis demotes it to per-lane VMEM = v2 disease).
// k_assign (scalar path, validated in v5) and tail unchanged.
// All fmaf chain orders preserved bit-exactly -> z, distances, argmin
// unchanged.

__device__ __forceinline__ unsigned ford(float s) {
    // order-preserving map float -> unsigned (total order, matches < on floats)
    unsigned b = __float_as_uint(s);
    return (b & 0x80000000u) ? ~b : (b | 0x80000000u);
}

// ---------------- K1: z = x @ enc_w  ([65536,256]x[256,64]) ----------------
// 1024 blocks x 256 thr (4 waves); block = 64 rows; lane = row, wave = d-quarter.
// x chunk staged in LDS pitch 65 (read bank (r+kk)%32 -> 2-way, free; b32
// stores unprovably-16B-aligned -> stay b32, safe).  w row quarter (uniform
// addr) -> one s_load_dwordx16 per kk.  acc[16] per thread.
// Chain: acc[d] += x[k]*w[k][d] for k ascending == the verified nested-fmaf
// order -> bit-identical z.
__global__ __launch_bounds__(256) void k_encode(const float* __restrict__ x,
                                                const float* __restrict__ enc_w,
                                                float* __restrict__ z) {
    __shared__ float xs[64 * 65];  // pitch 65 floats, 16640 B -> 4 blocks/CU

    int t = threadIdx.x;
    int row0 = blockIdx.x * 64;
    int rl = t & 63;                                      // lane = local row
    int dq = __builtin_amdgcn_readfirstlane(t >> 6);      // wave = d-quarter (SGPR!)
    const float* wq = enc_w + dq * 16;

    float acc[16];
#pragma unroll
    for (int j = 0; j < 16; ++j) acc[j] = 0.f;

    const float4* xg = (const float4*)x;  // x row = 64 float4

    for (int c = 0; c < 4; ++c) {
        __syncthreads();  // prior chunk's readers done
        // stage chunk: 64 rows x 16 f4 = 1024 f4; thread t -> f4 idx t+256j.
        // global: 4x 256B segments per wave inst (coalesced).  LDS: b32
        // stores, 2-way bank alias -> free.
#pragma unroll
        for (int j = 0; j < 4; ++j) {
            int idx = t + 256 * j;
            int r = idx >> 4, col = idx & 15;
            float4 v = xg[(size_t)(row0 + r) * 64 + c * 16 + col];
            float* p = &xs[r * 65 + col * 4];
            p[0] = v.x;
            p[1] = v.y;
            p[2] = v.z;
            p[3] = v.w;
        }
        __syncthreads();

#pragma unroll 4
        for (int kk = 0; kk < 64; ++kk) {
            float xv = xs[rl * 65 + kk];  // 2-way bank alias: free
            const float* w = wq + (size_t)(c * 64 + kk) * 64;  // uniform -> s_load_dwordx16
#pragma unroll
            for (int j = 0; j < 16; ++j) acc[j] = fmaf(xv, w[j], acc[j]);
        }
    }
    float4* z4 = (float4*)z + (size_t)(row0 + rl) * 16 + dq * 4;
#pragma unroll
    for (int j = 0; j < 4; ++j)
        z4[j] = make_float4(acc[4 * j + 0], acc[4 * j + 1], acc[4 * j + 2], acc[4 * j + 3]);
}

// ---------------- K2: nearest-code assignment ----------------
// (v5 verbatim -- scalar-pipe path validated)
// 1024 blocks (quarter-major: bid = q*256 + row_tile) x 256 thr (4 waves).
// Lane owns ONE z-row pinned in 64 VGPRs; iterates its quarter's 128 codes.
// Per code: 4x s_load_dwordx16 (codebook row, uniform addr) + 64 FMA w/ SGPR
// operand + key update.  ZERO LDS in the loop.  Per-lane best key -> one
// u64 atomicMin per (row, quarter).
// NUMERICS: d0..d3 fmaf chains ascending j, s=(zz+ee)-2f*dot, min-key
// tie-break lowest code -> bit-identical argmin to verified versions.
__global__ __launch_bounds__(256) void k_assign(const float* __restrict__ z,
                                                const float* __restrict__ cb,
                                                const float* __restrict__ eesq,
                                                unsigned long long* __restrict__ part) {
    int t = threadIdx.x, lane = t & 63, wv = t >> 6;
    int q = blockIdx.x >> 8;    // code quarter (4)
    int rt = blockIdx.x & 255;  // row tile (256)
    int c0 = q * 128;
    int row = rt * 256 + wv * 64 + lane;  // lane's row

    // load lane's z-row into regs and PIN (prevent remat-from-global)
    const float4* zr4 = (const float4*)z + (size_t)row * 16;
    float4 zr[16];
#pragma unroll
    for (int j = 0; j < 16; ++j) zr[j] = zr4[j];
#pragma unroll
    for (int j = 0; j < 16; ++j)
        asm volatile("" : "+v"(zr[j].x), "+v"(zr[j].y), "+v"(zr[j].z), "+v"(zr[j].w));

    // zz from regs (exact verified chain)
    float zz;
    {
        float a0 = 0, a1 = 0, a2 = 0, a3 = 0;
#pragma unroll
        for (int j = 0; j < 16; ++j) {
            a0 = fmaf(zr[j].x, zr[j].x, a0);
            a1 = fmaf(zr[j].y, zr[j].y, a1);
            a2 = fmaf(zr[j].z, zr[j].z, a2);
            a3 = fmaf(zr[j].w, zr[j].w, a3);
        }
        zz = (a0 + a1) + (a2 + a3);
    }

    unsigned long long best = ~0ull;
#pragma unroll 2
    for (int c = 0; c < 128; ++c) {
        const float* e = cb + (size_t)(c0 + c) * 64;  // uniform addr -> s_load
        float d0 = 0, d1 = 0, d2 = 0, d3 = 0;
#pragma unroll
        for (int j = 0; j < 16; ++j) {
            d0 = fmaf(zr[j].x, e[4 * j + 0], d0);
            d1 = fmaf(zr[j].y, e[4 * j + 1], d1);
            d2 = fmaf(zr[j].z, e[4 * j + 2], d2);
            d3 = fmaf(zr[j].w, e[4 * j + 3], d3);
        }
        float ee = eesq[c0 + c];  // uniform -> s_load
        float dot = (d0 + d1) + (d2 + d3);
        float s = (zz + ee) - 2.0f * dot;  // reference-matching fp32 rounding
        unsigned long long k = ((unsigned long long)ford(s) << 32) | (unsigned)(c0 + c);
        if (k < best) best = k;
    }
    atomicMin(&part[row], best);
}

// ---------------- K3a: cr = codebook @ dec_w + eesq ----------------
// (v5 verbatim)
__global__ __launch_bounds__(256) void k_coderecon(const float* __restrict__ cb,
                                                   const float* __restrict__ dec_w,
                                                   float* __restrict__ cr,
                                                   float* __restrict__ eesq) {
    __shared__ float qs[32 * 64];  // 8 KB

    int t = threadIdx.x;
    int r0 = blockIdx.x * 32;
    {
        const float4* cb4 = (const float4*)cb;
        float4* qs4 = (float4*)qs;
#pragma unroll
        for (int j = 0; j < 2; ++j) qs4[t + 256 * j] = cb4[r0 * 16 + t + 256 * j];
    }
    __syncthreads();

    if (t < 32) {  // eesq: exact verified 4-chain
        const float4* q4 = (const float4*)qs + t * 16;
        float n0 = 0, n1 = 0, n2 = 0, n3 = 0;
#pragma unroll
        for (int j = 0; j < 16; ++j) {
            float4 e = q4[j];
            n0 = fmaf(e.x, e.x, n0);
            n1 = fmaf(e.y, e.y, n1);
            n2 = fmaf(e.z, e.z, n2);
            n3 = fmaf(e.w, e.w, n3);
        }
        eesq[r0 + t] = (n0 + n1) + (n2 + n3);
    }

    int l = t & 63, w = t >> 6;  // wave w -> codes w*8..w*8+7; lane -> 4 columns
    const float4* dw4 = (const float4*)dec_w;
    float4 acc[8];
#pragma unroll
    for (int j = 0; j < 8; ++j) acc[j] = make_float4(0.f, 0.f, 0.f, 0.f);

#pragma unroll 4
    for (int d = 0; d < 64; ++d) {
        float4 wv = dw4[d * 64 + l];  // global, coalesced, L2-resident
#pragma unroll
        for (int j = 0; j < 8; ++j) {
            float qv = qs[(w * 8 + j) * 64 + d];  // broadcast (tiny kernel)
            acc[j].x = fmaf(qv, wv.x, acc[j].x);
            acc[j].y = fmaf(qv, wv.y, acc[j].y);
            acc[j].z = fmaf(qv, wv.z, acc[j].z);
            acc[j].w = fmaf(qv, wv.w, acc[j].w);
        }
    }
    float4* cr4 = (float4*)cr;
#pragma unroll
    for (int j = 0; j < 8; ++j) cr4[(size_t)(r0 + w * 8 + j) * 64 + l] = acc[j];
}

// ---------------- K3b: fused finish: gather + sse + counts ----------------
// (v5 verbatim)
__global__ __launch_bounds__(256) void k_finish(const unsigned long long* __restrict__ part,
                                                const float* __restrict__ z,
                                                const float* __restrict__ cb,
                                                const float* __restrict__ cr,
                                                float* __restrict__ out1,
                                                double* __restrict__ spart,
                                                int* __restrict__ counts) {
    __shared__ double red[4];
    __shared__ int hist[512];
    int t = threadIdx.x, l = t & 63, w = t >> 6;
    int row0 = blockIdx.x * 32 + w * 8;

    hist[t] = 0;
    hist[t + 256] = 0;
    __syncthreads();

    unsigned long long myk = part[row0 + (l & 7)];  // 8 keys, 8-way duplicated
    double acc = 0.0;
#pragma unroll
    for (int i = 0; i < 8; ++i) {
        int row = row0 + i;
        int kb = (int)(__shfl(myk, i) & 0xffffffffu);
        if (l == 0) atomicAdd(&hist[kb], 1);
        // sse slice: this lane handles dim d = l
        float zv = z[(size_t)row * 64 + l];
        float qv = cb[(size_t)kb * 64 + l];
        float f = qv - zv;
        acc += (double)f * f;
        // reconstruction row copy
        const float* crr = cr + (size_t)kb * 256;
        float* o = out1 + (size_t)row * 256;
#pragma unroll
        for (int j = 0; j < 4; ++j) o[l + 64 * j] = crr[l + 64 * j];
    }
#pragma unroll
    for (int off = 32; off >= 1; off >>= 1) acc += __shfl_down(acc, off);
    if (l == 0) red[w] = acc;
    __syncthreads();
    if (t == 0) spart[blockIdx.x] = (red[0] + red[1]) + (red[2] + red[3]);
    if (hist[t]) atomicAdd(&counts[t], hist[t]);
    if (hist[t + 256]) atomicAdd(&counts[t + 256], hist[t + 256]);
}

// ---------------- K4: loss + perplexity scalars ----------------
// (v5 verbatim)
__global__ __launch_bounds__(512) void k_final(const double* __restrict__ spart,
                                               const int* __restrict__ counts,
                                               float* __restrict__ out_loss,
                                               float* __restrict__ out_pp) {
    __shared__ double redp[8], reds[8];
    int t = threadIdx.x;
    double p = (double)counts[t] / 65536.0;
    double term = p * log(p + 1e-10);
    double s = 0.0;
#pragma unroll
    for (int j = 0; j < 4; ++j) s += spart[t + 512 * j];
#pragma unroll
    for (int off = 32; off >= 1; off >>= 1) {
        term += __shfl_down(term, off);
        s += __shfl_down(s, off);
    }
    if ((t & 63) == 0) {
        redp[t >> 6] = term;
        reds[t >> 6] = s;
    }
    __syncthreads();
    if (t == 0) {
        double st = 0, ss = 0;
#pragma unroll
        for (int w = 0; w < 8; ++w) {
            st += redp[w];
            ss += reds[w];
        }
        out_pp[0] = (float)exp(-st);
        out_loss[0] = (float)(1.25 * ss / 4194304.0);  // (1+0.25)*mean((q-z)^2)
    }
}

extern "C" void kernel_launch(void* const* d_in, const int* in_sizes, int n_in,
                              void* d_out, int out_size, void* d_ws, size_t ws_size,
                              hipStream_t stream) {
    const float* x = (const float*)d_in[0];
    const float* enc_w = (const float*)d_in[1];
    const float* dec_w = (const float*)d_in[2];
    const float* cb = (const float*)d_in[3];
    float* out = (float*)d_out;

    char* ws = (char*)d_ws;
    float* z = (float*)ws;                                            // 16 MiB
    unsigned long long* part = (unsigned long long*)(ws + 16777216);  // 512 KiB
    float* cr = (float*)(ws + 17301504);                              // 512 KiB
    int* counts = (int*)(ws + 17825792);                              // 2 KiB
    double* spart = (double*)(ws + 17827840);                         // 16 KiB
    float* eesq = (float*)(ws + 17844224);                            // 2 KiB

    // ws is poisoned to 0xAA before each launch
    hipMemsetAsync(ws + 16777216, 0xFF, 524288, stream);  // part -> max keys
    hipMemsetAsync(ws + 17825792, 0, 2048, stream);       // counts -> 0

    k_coderecon<<<dim3(16), dim3(256), 0, stream>>>(cb, dec_w, cr, eesq);
    k_encode<<<dim3(1024), dim3(256), 0, stream>>>(x, enc_w, z);
    k_assign<<<dim3(1024), dim3(256), 0, stream>>>(z, cb, eesq, part);
    k_finish<<<dim3(2048), dim3(256), 0, stream>>>(part, z, cb, cr, out + 1, spart, counts);
    k_final<<<dim3(1), dim3(512), 0, stream>>>(spart, counts, out, out + 16777217);
}

// Round 6
// 237.477 us; speedup vs baseline: 1.3293x; 1.0781x over previous
//
#include <hip/hip_runtime.h>

// VQ-VAE forward on MI355X, fp32 (no fp32 MFMA on CDNA4 -> vector ALU).
// N = 65536 rows, IN_DIM=256, D=64, K=512.
//
// ws layout (bytes):
//   z:      float[65536*64]        @ 0          (16 MiB)
//   part:   ull[65536]             @ 16777216   (512 KiB)  argmin keys
//   cr:     float[512*256]         @ 17301504   (512 KiB)  = codebook @ dec_w
//   counts: int[512]               @ 17825792   (2 KiB)
//   spart:  double[2048]           @ 17827840   (16 KiB)   per-block sse partials
//   eesq:   float[512]             @ 17844224   (2 KiB)    ||e||^2 per code
//
// v7: v6's k_assign measured 74us, VALUBusy 54% at 16 waves/CU, VGPR=40,
// LDS=0, SGPR=96.  Per-wave VALU duty ~13.5% -> per code 128 FMA-cycles vs
// ~800 stall cycles (4x s_load_dwordx16 K$-miss serialized; SGPR budget
// forbids deeper prefetch).  Duty is structural; utilization = duty x
// waves/SIMD.  With VGPR=40 / LDS=0 nothing caps occupancy but the grid
// -> split codes 8 ways (grid 2048) for 32 waves/CU = saturation.
// Also: coderecon fused into the encode launch (k_front) + in-kernel
// part/counts init -> 4 stream ops total (was 5 kernels + 2 memsets).
// All fmaf chain orders preserved bit-exactly -> z, distances, argmin
// unchanged (slice partitioning only re-groups the same min-key reduction).

__device__ __forceinline__ unsigned ford(float s) {
    // order-preserving map float -> unsigned (total order, matches < on floats)
    unsigned b = __float_as_uint(s);
    return (b & 0x80000000u) ? ~b : (b | 0x80000000u);
}

// ---------------- K1: fused front: coderecon (blocks 0..15) + encode ----------------
// encode: 1024 blocks x 256 thr (4 waves); block = 64 rows; lane = row,
// wave = d-quarter.  x chunk staged in LDS pitch 65 (read bank (r+kk)%32 ->
// 2-way, free; b32 stores unprovably-16B-aligned -> stay b32, safe).  w row
// quarter (uniform addr via readfirstlane) -> one s_load_dwordx16 per kk.
// Chain: acc[d] += x[k]*w[k][d] for k ascending == the verified nested-fmaf
// order -> bit-identical z.  Each encode block also inits its 64 part[] keys
// (stream-ordered before k_assign).
// coderecon: block does 32 codes; dec_w streamed from L2; also emits
// eesq[code] = ||e||^2 (exact verified chain) and zeroes counts[].
__global__ __launch_bounds__(256) void k_front(const float* __restrict__ x,
                                               const float* __restrict__ enc_w,
                                               const float* __restrict__ cb,
                                               const float* __restrict__ dec_w,
                                               float* __restrict__ z,
                                               float* __restrict__ cr,
                                               float* __restrict__ eesq,
                                               int* __restrict__ counts,
                                               unsigned long long* __restrict__ part) {
    __shared__ __align__(16) float xs[64 * 65];  // 16640 B (also hosts qs 8KB)

    int t = threadIdx.x;

    if (blockIdx.x < 16) {
        // ---------- coderecon path (v6 k_coderecon, qs := xs) ----------
        float* qs = xs;
        int r0 = blockIdx.x * 32;
        if (t < 32) counts[blockIdx.x * 32 + t] = 0;  // counts init (512 total)
        {
            const float4* cb4 = (const float4*)cb;
            float4* qs4 = (float4*)qs;
#pragma unroll
            for (int j = 0; j < 2; ++j) qs4[t + 256 * j] = cb4[r0 * 16 + t + 256 * j];
        }
        __syncthreads();

        if (t < 32) {  // eesq: exact verified 4-chain
            const float4* q4 = (const float4*)qs + t * 16;
            float n0 = 0, n1 = 0, n2 = 0, n3 = 0;
#pragma unroll
            for (int j = 0; j < 16; ++j) {
                float4 e = q4[j];
                n0 = fmaf(e.x, e.x, n0);
                n1 = fmaf(e.y, e.y, n1);
                n2 = fmaf(e.z, e.z, n2);
                n3 = fmaf(e.w, e.w, n3);
            }
            eesq[r0 + t] = (n0 + n1) + (n2 + n3);
        }

        int l = t & 63, w = t >> 6;  // wave w -> codes w*8..w*8+7; lane -> 4 cols
        const float4* dw4 = (const float4*)dec_w;
        float4 acc[8];
#pragma unroll
        for (int j = 0; j < 8; ++j) acc[j] = make_float4(0.f, 0.f, 0.f, 0.f);

#pragma unroll 4
        for (int d = 0; d < 64; ++d) {
            float4 wv = dw4[d * 64 + l];  // global, coalesced, L2-resident
#pragma unroll
            for (int j = 0; j < 8; ++j) {
                float qv = qs[(w * 8 + j) * 64 + d];  // broadcast (tiny kernel)
                acc[j].x = fmaf(qv, wv.x, acc[j].x);
                acc[j].y = fmaf(qv, wv.y, acc[j].y);
                acc[j].z = fmaf(qv, wv.z, acc[j].z);
                acc[j].w = fmaf(qv, wv.w, acc[j].w);
            }
        }
        float4* cr4 = (float4*)cr;
#pragma unroll
        for (int j = 0; j < 8; ++j) cr4[(size_t)(r0 + w * 8 + j) * 64 + l] = acc[j];
        return;
    }

    // ---------- encode path (v6 k_encode) ----------
    int bid = blockIdx.x - 16;
    if (t < 64) part[(size_t)bid * 64 + t] = ~0ull;  // init this block's rows' keys

    int row0 = bid * 64;
    int rl = t & 63;                                  // lane = local row
    int dq = __builtin_amdgcn_readfirstlane(t >> 6);  // wave = d-quarter (SGPR!)
    const float* wq = enc_w + dq * 16;

    float acc[16];
#pragma unroll
    for (int j = 0; j < 16; ++j) acc[j] = 0.f;

    const float4* xg = (const float4*)x;  // x row = 64 float4

    for (int c = 0; c < 4; ++c) {
        __syncthreads();  // prior chunk's readers done
        // stage chunk: 64 rows x 16 f4 = 1024 f4; thread t -> f4 idx t+256j.
        // global: coalesced.  LDS: b32 stores, 2-way bank alias -> free.
#pragma unroll
        for (int j = 0; j < 4; ++j) {
            int idx = t + 256 * j;
            int r = idx >> 4, col = idx & 15;
            float4 v = xg[(size_t)(row0 + r) * 64 + c * 16 + col];
            float* p = &xs[r * 65 + col * 4];
            p[0] = v.x;
            p[1] = v.y;
            p[2] = v.z;
            p[3] = v.w;
        }
        __syncthreads();

#pragma unroll 4
        for (int kk = 0; kk < 64; ++kk) {
            float xv = xs[rl * 65 + kk];  // 2-way bank alias: free
            const float* w = wq + (size_t)(c * 64 + kk) * 64;  // uniform -> s_load_dwordx16
#pragma unroll
            for (int j = 0; j < 16; ++j) acc[j] = fmaf(xv, w[j], acc[j]);
        }
    }
    float4* z4 = (float4*)z + (size_t)(row0 + rl) * 16 + dq * 4;
#pragma unroll
    for (int j = 0; j < 4; ++j)
        z4[j] = make_float4(acc[4 * j + 0], acc[4 * j + 1], acc[4 * j + 2], acc[4 * j + 3]);
}

// ---------------- K2: nearest-code assignment ----------------
// 2048 blocks (slice-major: bid = s*256 + row_tile, 8 slices of 64 codes)
// x 256 thr (4 waves).  Lane owns ONE z-row pinned in 64 VGPRs; iterates its
// slice's 64 codes.  Per code: 4x s_load_dwordx16 (codebook row, uniform
// addr) + 64 FMA w/ SGPR operand + key update.  ZERO LDS.  VGPR=40 ->
// 8 blocks/CU = 32 waves/CU (v6 was 16): per-wave duty ~13.5% x 8 waves/SIMD
// -> VALU saturation.  Per-lane best key -> one u64 atomicMin per
// (row, slice).
// NUMERICS: d0..d3 fmaf chains ascending j, s=(zz+ee)-2f*dot, min-key
// tie-break lowest code -> bit-identical argmin to verified versions.
__global__ __launch_bounds__(256) void k_assign(const float* __restrict__ z,
                                                const float* __restrict__ cb,
                                                const float* __restrict__ eesq,
                                                unsigned long long* __restrict__ part) {
    int t = threadIdx.x, lane = t & 63, wv = t >> 6;
    int s8 = blockIdx.x >> 8;   // code slice (8)
    int rt = blockIdx.x & 255;  // row tile (256)
    int c0 = s8 * 64;
    int row = rt * 256 + wv * 64 + lane;  // lane's row

    // load lane's z-row into regs and PIN (prevent remat-from-global)
    const float4* zr4 = (const float4*)z + (size_t)row * 16;
    float4 zr[16];
#pragma unroll
    for (int j = 0; j < 16; ++j) zr[j] = zr4[j];
#pragma unroll
    for (int j = 0; j < 16; ++j)
        asm volatile("" : "+v"(zr[j].x), "+v"(zr[j].y), "+v"(zr[j].z), "+v"(zr[j].w));

    // zz from regs (exact verified chain)
    float zz;
    {
        float a0 = 0, a1 = 0, a2 = 0, a3 = 0;
#pragma unroll
        for (int j = 0; j < 16; ++j) {
            a0 = fmaf(zr[j].x, zr[j].x, a0);
            a1 = fmaf(zr[j].y, zr[j].y, a1);
            a2 = fmaf(zr[j].z, zr[j].z, a2);
            a3 = fmaf(zr[j].w, zr[j].w, a3);
        }
        zz = (a0 + a1) + (a2 + a3);
    }

    unsigned long long best = ~0ull;
#pragma unroll 2
    for (int c = 0; c < 64; ++c) {
        const float* e = cb + (size_t)(c0 + c) * 64;  // uniform addr -> s_load
        float d0 = 0, d1 = 0, d2 = 0, d3 = 0;
#pragma unroll
        for (int j = 0; j < 16; ++j) {
            d0 = fmaf(zr[j].x, e[4 * j + 0], d0);
            d1 = fmaf(zr[j].y, e[4 * j + 1], d1);
            d2 = fmaf(zr[j].z, e[4 * j + 2], d2);
            d3 = fmaf(zr[j].w, e[4 * j + 3], d3);
        }
        float ee = eesq[c0 + c];  // uniform -> s_load
        float dot = (d0 + d1) + (d2 + d3);
        float s = (zz + ee) - 2.0f * dot;  // reference-matching fp32 rounding
        unsigned long long k = ((unsigned long long)ford(s) << 32) | (unsigned)(c0 + c);
        if (k < best) best = k;
    }
    atomicMin(&part[row], best);
}

// ---------------- K3: fused finish: gather + sse + counts ----------------
// (v5/v6 verbatim) 2048 blocks x 256 thr; wave = 8 rows.  LDS hist cuts
// global atomics; lane l writes out1[row*256 + l + 64j] -> 256 B contiguous
// dword segments (out is 4B-aligned only).
__global__ __launch_bounds__(256) void k_finish(const unsigned long long* __restrict__ part,
                                                const float* __restrict__ z,
                                                const float* __restrict__ cb,
                                                const float* __restrict__ cr,
                                                float* __restrict__ out1,
                                                double* __restrict__ spart,
                                                int* __restrict__ counts) {
    __shared__ double red[4];
    __shared__ int hist[512];
    int t = threadIdx.x, l = t & 63, w = t >> 6;
    int row0 = blockIdx.x * 32 + w * 8;

    hist[t] = 0;
    hist[t + 256] = 0;
    __syncthreads();

    unsigned long long myk = part[row0 + (l & 7)];  // 8 keys, 8-way duplicated
    double acc = 0.0;
#pragma unroll
    for (int i = 0; i < 8; ++i) {
        int row = row0 + i;
        int kb = (int)(__shfl(myk, i) & 0xffffffffu);
        if (l == 0) atomicAdd(&hist[kb], 1);
        // sse slice: this lane handles dim d = l
        float zv = z[(size_t)row * 64 + l];
        float qv = cb[(size_t)kb * 64 + l];
        float f = qv - zv;
        acc += (double)f * f;
        // reconstruction row copy
        const float* crr = cr + (size_t)kb * 256;
        float* o = out1 + (size_t)row * 256;
#pragma unroll
        for (int j = 0; j < 4; ++j) o[l + 64 * j] = crr[l + 64 * j];
    }
#pragma unroll
    for (int off = 32; off >= 1; off >>= 1) acc += __shfl_down(acc, off);
    if (l == 0) red[w] = acc;
    __syncthreads();
    if (t == 0) spart[blockIdx.x] = (red[0] + red[1]) + (red[2] + red[3]);
    if (hist[t]) atomicAdd(&counts[t], hist[t]);
    if (hist[t + 256]) atomicAdd(&counts[t + 256], hist[t + 256]);
}

// ---------------- K4: loss + perplexity scalars ----------------
// (v5/v6 verbatim)
__global__ __launch_bounds__(512) void k_final(const double* __restrict__ spart,
                                               const int* __restrict__ counts,
                                               float* __restrict__ out_loss,
                                               float* __restrict__ out_pp) {
    __shared__ double redp[8], reds[8];
    int t = threadIdx.x;
    double p = (double)counts[t] / 65536.0;
    double term = p * log(p + 1e-10);
    double s = 0.0;
#pragma unroll
    for (int j = 0; j < 4; ++j) s += spart[t + 512 * j];
#pragma unroll
    for (int off = 32; off >= 1; off >>= 1) {
        term += __shfl_down(term, off);
        s += __shfl_down(s, off);
    }
    if ((t & 63) == 0) {
        redp[t >> 6] = term;
        reds[t >> 6] = s;
    }
    __syncthreads();
    if (t == 0) {
        double st = 0, ss = 0;
#pragma unroll
        for (int w = 0; w < 8; ++w) {
            st += redp[w];
            ss += reds[w];
        }
        out_pp[0] = (float)exp(-st);
        out_loss[0] = (float)(1.25 * ss / 4194304.0);  // (1+0.25)*mean((q-z)^2)
    }
}

extern "C" void kernel_launch(void* const* d_in, const int* in_sizes, int n_in,
                              void* d_out, int out_size, void* d_ws, size_t ws_size,
                              hipStream_t stream) {
    const float* x = (const float*)d_in[0];
    const float* enc_w = (const float*)d_in[1];
    const float* dec_w = (const float*)d_in[2];
    const float* cb = (const float*)d_in[3];
    float* out = (float*)d_out;

    char* ws = (char*)d_ws;
    float* z = (float*)ws;                                            // 16 MiB
    unsigned long long* part = (unsigned long long*)(ws + 16777216);  // 512 KiB
    float* cr = (float*)(ws + 17301504);                              // 512 KiB
    int* counts = (int*)(ws + 17825792);                              // 2 KiB
    double* spart = (double*)(ws + 17827840);                         // 16 KiB
    float* eesq = (float*)(ws + 17844224);                            // 2 KiB

    // ws is poisoned to 0xAA before each launch; all accumulators are
    // initialized in-kernel (part/counts by k_front, spart by k_finish).
    k_front<<<dim3(1040), dim3(256), 0, stream>>>(x, enc_w, cb, dec_w, z, cr, eesq,
                                                  counts, part);
    k_assign<<<dim3(2048), dim3(256), 0, stream>>>(z, cb, eesq, part);
    k_finish<<<dim3(2048), dim3(256), 0, stream>>>(part, z, cb, cr, out + 1, spart, counts);
    k_final<<<dim3(1), dim3(512), 0, stream>>>(spart, counts, out, out + 16777217);
}

// Round 7
// 206.572 us; speedup vs baseline: 1.5281x; 1.1496x over previous
//
#include <hip/hip_runtime.h>

// VQ-VAE forward on MI355X, fp32 (no fp32 MFMA on CDNA4 -> vector ALU).
// N = 65536 rows, IN_DIM=256, D=64, K=512.
//
// ws layout (bytes):
//   cr:     float[512*256]         @ 17301504   (512 KiB)  = codebook @ dec_w
//   counts: int[512]               @ 17825792   (2 KiB)
//   spart:  double[1024]           @ 17827840   (8 KiB)    per-block sse partials
//   eesq:   float[512]             @ 17844224   (2 KiB)    ||e||^2 per code
//   (z / part / idx eliminated in v8 -- z lives in LDS only)
//
// v8: fusion.  v7 counters: assign 69.8us VALUBusy 59.6% (VALU-issue ~41.6us
// vs 31.6us FMA floor -> issue-bound-ish; occupancy attacks exhausted), and
// the pipeline pays full global round-trips for z (16MiB w+r+r), part
// (atomicMin w+r) plus 4 launches.  Fix: one mega-kernel per 64-row block:
//   encode (v7 path, z -> LDS)  ->  lane pulls its row into 64 VGPRs  ->
//   scalar-pipe code loop (v7-verified, 128 codes/wave)  ->  in-LDS u64
//   key-min across 4 waves  ->  v5-verified finish (sse/hist/out copy)
// using in-LDS kb.  No z/part/idx global traffic at all.
// All argmin-relevant fmaf chains byte-identical to v7 -> bit-identical
// argmin.  sse remains double-accumulated (order-robust, tolerance-checked).

__device__ __forceinline__ unsigned ford(float s) {
    // order-preserving map float -> unsigned (total order, matches < on floats)
    unsigned b = __float_as_uint(s);
    return (b & 0x80000000u) ? ~b : (b | 0x80000000u);
}

// ---------------- K1: front: cr = codebook @ dec_w, eesq, counts=0 ----------------
// 64 blocks x 256 thr; block does 8 codes (wave = 2 codes, lane = 4 cols).
// Per-(code,col) chain: acc = fmaf(q, wv, acc) over d ascending == verified
// v5/v6/v7 coderecon chain -> cr bit-identical.  eesq = exact verified
// n0..n3 chain.
__global__ __launch_bounds__(256) void k_front(const float* __restrict__ cb,
                                               const float* __restrict__ dec_w,
                                               float* __restrict__ cr,
                                               float* __restrict__ eesq,
                                               int* __restrict__ counts) {
    __shared__ float qs[8 * 64];  // 2 KB

    int t = threadIdx.x;
    int r0 = blockIdx.x * 8;
    if (t < 8) counts[r0 + t] = 0;  // counts init (64 blocks x 8 = 512)
    if (t < 128) ((float4*)qs)[t] = ((const float4*)cb)[r0 * 16 + t];
    __syncthreads();

    if (t < 8) {  // eesq: exact verified 4-chain
        const float4* q4 = (const float4*)qs + t * 16;
        float n0 = 0, n1 = 0, n2 = 0, n3 = 0;
#pragma unroll
        for (int j = 0; j < 16; ++j) {
            float4 e = q4[j];
            n0 = fmaf(e.x, e.x, n0);
            n1 = fmaf(e.y, e.y, n1);
            n2 = fmaf(e.z, e.z, n2);
            n3 = fmaf(e.w, e.w, n3);
        }
        eesq[r0 + t] = (n0 + n1) + (n2 + n3);
    }

    int l = t & 63, w = t >> 6;  // wave w -> codes r0+2w, r0+2w+1; lane -> 4 cols
    const float4* dw4 = (const float4*)dec_w;
    float4 a0 = make_float4(0.f, 0.f, 0.f, 0.f);
    float4 a1 = make_float4(0.f, 0.f, 0.f, 0.f);

#pragma unroll 4
    for (int d = 0; d < 64; ++d) {
        float4 wv = dw4[d * 64 + l];  // global, coalesced, L2-resident
        float q0 = qs[(w * 2 + 0) * 64 + d];  // broadcast (tiny kernel)
        float q1 = qs[(w * 2 + 1) * 64 + d];
        a0.x = fmaf(q0, wv.x, a0.x);
        a0.y = fmaf(q0, wv.y, a0.y);
        a0.z = fmaf(q0, wv.z, a0.z);
        a0.w = fmaf(q0, wv.w, a0.w);
        a1.x = fmaf(q1, wv.x, a1.x);
        a1.y = fmaf(q1, wv.y, a1.y);
        a1.z = fmaf(q1, wv.z, a1.z);
        a1.w = fmaf(q1, wv.w, a1.w);
    }
    float4* cr4 = (float4*)cr;
    cr4[(size_t)(r0 + w * 2 + 0) * 64 + l] = a0;
    cr4[(size_t)(r0 + w * 2 + 1) * 64 + l] = a1;
}

// ---------------- K2: mega: encode + assign + finish ----------------
// 1024 blocks x 256 thr (4 waves); block = 64 rows.
// Phase E (v7 encode): lane = row, wave = d-quarter (readfirstlane -> SGPR);
//   x chunk in LDS pitch 65 (2-way banks, free); w quarter via
//   s_load_dwordx16; acc[d] += x[k]*w[k][d], k ascending -> bit-identical z.
//   z written to LDS (NOT global).
// Phase A (v7 assign): lane pulls row l into 64 pinned VGPRs; wave cq
//   handles codes cq*128..+128 via s_load (zero LDS/VMEM in loop); exact
//   d0..d3 / s=(zz+ee)-2f*dot / min-key chains -> bit-identical argmin.
//   4 per-wave candidates -> LDS u64 min (assoc; ties carry same key).
// Phase F (v5 finish): wave = 16 rows; sse slice (lane=dim, double), LDS
//   hist, coalesced cr->out copy (out is 4B-aligned only -> dword stores).
__global__ __launch_bounds__(256, 4) void k_mega(const float* __restrict__ x,
                                                 const float* __restrict__ enc_w,
                                                 const float* __restrict__ cb,
                                                 const float* __restrict__ eesq,
                                                 const float* __restrict__ cr,
                                                 float* __restrict__ out1,
                                                 double* __restrict__ spart,
                                                 int* __restrict__ counts) {
    __shared__ float zs[64 * 65];                // 16640 B: x staging, then z
    __shared__ unsigned long long pl[4 * 64];    // per-(wave,row) best key, 2 KB
    __shared__ int kbl[64];
    __shared__ int hist[512];
    __shared__ double red[4];

    int t = threadIdx.x, l = t & 63, wv = t >> 6;
    int row0 = blockIdx.x * 64;

    hist[t] = 0;
    hist[t + 256] = 0;

    // ---------------- Phase E: encode ----------------
    int dq = __builtin_amdgcn_readfirstlane(wv);  // wave = d-quarter (SGPR!)
    const float* wq = enc_w + dq * 16;

    float acc[16];
#pragma unroll
    for (int j = 0; j < 16; ++j) acc[j] = 0.f;

    const float4* xg = (const float4*)x;  // x row = 64 float4

    for (int c = 0; c < 4; ++c) {
        __syncthreads();  // prior chunk's readers done
        // stage chunk: 64 rows x 16 f4; b32 stores (pitch 65 unprovably
        // 16B-aligned -> stay b32, safe); 2-way bank alias -> free.
#pragma unroll
        for (int j = 0; j < 4; ++j) {
            int idx = t + 256 * j;
            int r = idx >> 4, col = idx & 15;
            float4 v = xg[(size_t)(row0 + r) * 64 + c * 16 + col];
            float* p = &zs[r * 65 + col * 4];
            p[0] = v.x;
            p[1] = v.y;
            p[2] = v.z;
            p[3] = v.w;
        }
        __syncthreads();

#pragma unroll 4
        for (int kk = 0; kk < 64; ++kk) {
            float xv = zs[l * 65 + kk];  // 2-way bank alias: free
            const float* w = wq + (size_t)(c * 64 + kk) * 64;  // uniform -> s_load_dwordx16
#pragma unroll
            for (int j = 0; j < 16; ++j) acc[j] = fmaf(xv, w[j], acc[j]);
        }
    }
    __syncthreads();  // all x reads done -> reuse zs for z
#pragma unroll
    for (int j = 0; j < 16; ++j) zs[l * 65 + dq * 16 + j] = acc[j];  // 2-way, free
    __syncthreads();

    // ---------------- Phase A: assign ----------------
    // lane owns row l: pull into regs and PIN (prevent remat)
    float zr[64];
#pragma unroll
    for (int k = 0; k < 64; ++k) zr[k] = zs[l * 65 + k];  // 2-way, free
#pragma unroll
    for (int j = 0; j < 16; ++j)
        asm volatile("" : "+v"(zr[4 * j]), "+v"(zr[4 * j + 1]), "+v"(zr[4 * j + 2]),
                          "+v"(zr[4 * j + 3]));

    // zz from regs (exact verified chain)
    float zz;
    {
        float a0 = 0, a1 = 0, a2 = 0, a3 = 0;
#pragma unroll
        for (int j = 0; j < 16; ++j) {
            a0 = fmaf(zr[4 * j + 0], zr[4 * j + 0], a0);
            a1 = fmaf(zr[4 * j + 1], zr[4 * j + 1], a1);
            a2 = fmaf(zr[4 * j + 2], zr[4 * j + 2], a2);
            a3 = fmaf(zr[4 * j + 3], zr[4 * j + 3], a3);
        }
        zz = (a0 + a1) + (a2 + a3);
    }

    int cq = __builtin_amdgcn_readfirstlane(wv);  // wave = code slice (SGPR!)
    int c0 = cq * 128;
    unsigned long long best = ~0ull;
#pragma unroll 2
    for (int c = 0; c < 128; ++c) {
        const float* e = cb + (size_t)(c0 + c) * 64;  // uniform addr -> s_load
        float d0 = 0, d1 = 0, d2 = 0, d3 = 0;
#pragma unroll
        for (int j = 0; j < 16; ++j) {
            d0 = fmaf(zr[4 * j + 0], e[4 * j + 0], d0);
            d1 = fmaf(zr[4 * j + 1], e[4 * j + 1], d1);
            d2 = fmaf(zr[4 * j + 2], e[4 * j + 2], d2);
            d3 = fmaf(zr[4 * j + 3], e[4 * j + 3], d3);
        }
        float ee = eesq[c0 + c];  // uniform -> s_load
        float dot = (d0 + d1) + (d2 + d3);
        float s = (zz + ee) - 2.0f * dot;  // reference-matching fp32 rounding
        unsigned long long k = ((unsigned long long)ford(s) << 32) | (unsigned)(c0 + c);
        if (k < best) best = k;
    }
    pl[cq * 64 + l] = best;  // dword bank (2l)%32 -> 2-way, free
    __syncthreads();

    if (t < 64) {
        unsigned long long b = pl[t];
#pragma unroll
        for (int w = 1; w < 4; ++w) {
            unsigned long long p = pl[w * 64 + t];
            b = p < b ? p : b;  // u64 min, ties carry identical key
        }
        int kb = (int)(b & 0xffffffffu);
        kbl[t] = kb;
        atomicAdd(&hist[kb], 1);
    }
    __syncthreads();

    // ---------------- Phase F: finish ----------------
    // wave wv handles rows wv*16..wv*16+16; lane l = dim/col slice.
    double sacc = 0.0;
#pragma unroll
    for (int i = 0; i < 16; ++i) {
        int row = wv * 16 + i;
        int kb = kbl[row];  // LDS broadcast
        // sse slice: this lane handles dim d = l
        float zv = zs[row * 65 + l];        // 2-way, free
        float qv = cb[(size_t)kb * 64 + l]; // coalesced, L2-hit
        float f = qv - zv;
        sacc += (double)f * f;
        // reconstruction row copy: 256 B contiguous dword segments
        const float* crr = cr + (size_t)kb * 256;
        float* o = out1 + (size_t)(row0 + row) * 256;
#pragma unroll
        for (int j = 0; j < 4; ++j) o[l + 64 * j] = crr[l + 64 * j];
    }
#pragma unroll
    for (int off = 32; off >= 1; off >>= 1) sacc += __shfl_down(sacc, off);
    if (l == 0) red[wv] = sacc;
    __syncthreads();
    if (t == 0) spart[blockIdx.x] = (red[0] + red[1]) + (red[2] + red[3]);
    if (hist[t]) atomicAdd(&counts[t], hist[t]);
    if (hist[t + 256]) atomicAdd(&counts[t + 256], hist[t + 256]);
}

// ---------------- K3: loss + perplexity scalars ----------------
__global__ __launch_bounds__(512) void k_final(const double* __restrict__ spart,
                                               const int* __restrict__ counts,
                                               float* __restrict__ out_loss,
                                               float* __restrict__ out_pp) {
    __shared__ double redp[8], reds[8];
    int t = threadIdx.x;
    double p = (double)counts[t] / 65536.0;
    double term = p * log(p + 1e-10);
    double s = spart[t] + spart[t + 512];  // 1024 block partials
#pragma unroll
    for (int off = 32; off >= 1; off >>= 1) {
        term += __shfl_down(term, off);
        s += __shfl_down(s, off);
    }
    if ((t & 63) == 0) {
        redp[t >> 6] = term;
        reds[t >> 6] = s;
    }
    __syncthreads();
    if (t == 0) {
        double st = 0, ss = 0;
#pragma unroll
        for (int w = 0; w < 8; ++w) {
            st += redp[w];
            ss += reds[w];
        }
        out_pp[0] = (float)exp(-st);
        out_loss[0] = (float)(1.25 * ss / 4194304.0);  // (1+0.25)*mean((q-z)^2)
    }
}

extern "C" void kernel_launch(void* const* d_in, const int* in_sizes, int n_in,
                              void* d_out, int out_size, void* d_ws, size_t ws_size,
                              hipStream_t stream) {
    const float* x = (const float*)d_in[0];
    const float* enc_w = (const float*)d_in[1];
    const float* dec_w = (const float*)d_in[2];
    const float* cb = (const float*)d_in[3];
    float* out = (float*)d_out;

    char* ws = (char*)d_ws;
    float* cr = (float*)(ws + 17301504);    // 512 KiB
    int* counts = (int*)(ws + 17825792);    // 2 KiB
    double* spart = (double*)(ws + 17827840);  // 8 KiB (1024 blocks)
    float* eesq = (float*)(ws + 17844224);  // 2 KiB

    // ws is poisoned to 0xAA before each launch; all accumulators are
    // initialized in-kernel (counts by k_front, spart stored by k_mega).
    k_front<<<dim3(64), dim3(256), 0, stream>>>(cb, dec_w, cr, eesq, counts);
    k_mega<<<dim3(1024), dim3(256), 0, stream>>>(x, enc_w, cb, eesq, cr, out + 1,
                                                 spart, counts);
    k_final<<<dim3(1), dim3(512), 0, stream>>>(spart, counts, out, out + 16777217);
}